// Round 12
// baseline (252.553 us; speedup 1.0000x reference)
//
#include <hip/hip_runtime.h>
#include <cstdint>
#include <cstddef>

#define NN      10000
#define NE      320000
#define FINF    2
#define HIDN    64
#define OUTN    16
#define BBATCH  4
#define TSTEPS  12
#define NBROWS  (NN * BBATCH)                    // 40000 (n-major, row = n*B + b)
#define XTN     (TSTEPS * NN * BBATCH * FINF)    // 960000
#define CAP     96                               // bucket capacity; P(deg>96) ~ 1e-18

typedef _Float16 v8h __attribute__((ext_vector_type(8)));
typedef _Float16 v2h __attribute__((ext_vector_type(2)));
typedef float    v4f __attribute__((ext_vector_type(4)));

// ---------------- fused setup: transpose + bucket-scatter + param fold ------
// Grid 1250x256 = 320000 threads = 1/edge. Transpose: thread per (b,n), 96B
// coalesced read, 12 x 4B half2 writes. xAll[n][96] fp16, j = t*8 + b*2 + f.
// PP layout (floats):
//   [0)      Lzb[64][64]   (k-major [k][j])
//   [4096)   Lrb[64][64]
//   [8192)   Lhb[64][64]
//   [12288)  W2[3][2][64]  = Wg @ Lg_top
//   [12672)  b2[3][64]     = bg @ Lg_top + Lg_b
//   [12864)  lin_w[64][16]
//   [13888)  lin_b[16]     (total 13904)
__global__ void setup_kernel(const float* __restrict__ x,
                             const int* __restrict__ src, const int* __restrict__ dst,
                             const float* __restrict__ ew,
                             int* __restrict__ cnt, float* __restrict__ degf,
                             int2* __restrict__ bucket, _Float16* __restrict__ xAll,
                             const float* __restrict__ Wz, const float* __restrict__ bz,
                             const float* __restrict__ Wr, const float* __restrict__ br,
                             const float* __restrict__ Wh, const float* __restrict__ bh,
                             const float* __restrict__ Lz, const float* __restrict__ Lz_b,
                             const float* __restrict__ Lr, const float* __restrict__ Lr_b,
                             const float* __restrict__ Lh, const float* __restrict__ Lh_b,
                             const float* __restrict__ linw, const float* __restrict__ linb,
                             float* __restrict__ PP) {
    int idx = blockIdx.x * 256 + threadIdx.x;
    // transpose: thread per (b,n): read 24 consecutive floats, write 12 half2
    if (idx < BBATCH * NN) {
        int b = idx / NN;
        int n = idx - b * NN;
        const float* xp = x + (size_t)idx * (FINF * TSTEPS);   // (b*NN+n)*24
        v2h* xo = (v2h*)xAll;                                  // pair (f=0,f=1)
        #pragma unroll
        for (int t = 0; t < TSTEPS; ++t) {
            v2h p;
            p.x = (_Float16)xp[t];
            p.y = (_Float16)xp[TSTEPS + t];
            xo[n * 48 + t * 4 + b] = p;
        }
    }
    // bucket scatter by dst + weighted degree (1 edge per thread)
    if (idx < NE) {
        int d = dst[idx];
        int s = src[idx];
        float w = ew[idx];
        int p = atomicAdd(&cnt[d], 1);
        if (p < CAP) {
            int2 rec;
            rec.x = s;
            rec.y = __float_as_int(w);
            bucket[d * CAP + p] = rec;
        }
        atomicAdd(&degf[d], w);
    }
    // parameter folding
    if (idx < 13904) {
        const float* Lg[3]    = {Lz, Lr, Lh};
        const float* Lbias[3] = {Lz_b, Lr_b, Lh_b};
        const float* Wg[3]    = {Wz, Wr, Wh};
        const float* bg[3]    = {bz, br, bh};
        int i = idx;
        if (i < 12288) {
            int g = i >> 12, rr = (i >> 6) & 63, j = i & 63;
            PP[i] = Lg[g][(64 + rr) * 64 + j];
        } else if (i < 12672) {
            int i2 = i - 12288;
            int g = i2 >> 7, f = (i2 >> 6) & 1, j = i2 & 63;
            float s = 0.f;
            for (int k = 0; k < 64; ++k) s = fmaf(Wg[g][f * 64 + k], Lg[g][k * 64 + j], s);
            PP[i] = s;
        } else if (i < 12864) {
            int i3 = i - 12672;
            int g = i3 >> 6, j = i3 & 63;
            float s = Lbias[g][j];
            for (int k = 0; k < 64; ++k) s = fmaf(bg[g][k], Lg[g][k * 64 + j], s);
            PP[i] = s;
        } else if (i < 13888) {
            PP[i] = linw[i - 12864];
        } else {
            PP[i] = linb[i - 13888];
        }
    }
}

// ---------------- fused aggregate + recurrent GRU ----------------
// 625 blocks x 256 thr (4 waves, wave owns M=16 rows). Block bk's recurrent
// rows are exactly nodes 16bk..16bk+15 -> aggregate them into LDS (aggL) as a
// prologue (16 thr/node x 6 j's; per edge a node-group reads 192B contiguous
// from L2-resident fp16 xAll), one __syncthreads, then the R11 t-loop reading
// aggL instead of global agg. Z/R B-fragments in registers; H~ in LDS.
__device__ __forceinline__ float fsigmoid(float x) {
    return 1.0f / (1.0f + __expf(-x));
}

__global__ __launch_bounds__(256, 3)
void fused_kernel(const _Float16* __restrict__ xAll, const int2* __restrict__ bucket,
                  const int* __restrict__ cnt, const float* __restrict__ degf,
                  const float* __restrict__ PP, float* __restrict__ out) {
    __shared__ _Float16 WTH[64 * 72 + 32];      // H~: [n][k<64 | 64..66 init], pad
    __shared__ _Float16 WIZR[2 * 64 * 8 + 32];  // Z,R init: [g][n][0..7], pad
    __shared__ _Float16 Hm[4][16 * 72];         // per-wave H [row][col^swz]
    __shared__ float    aggL[16 * 96];          // block's 16 nodes x 96 (fp32)
    const int tid = threadIdx.x;
    const int w   = tid >> 6;
    const int l   = tid & 63;
    const int m   = l & 15;          // A row / B,C col within 16x16 tile
    const int q   = l >> 4;          // quad: A k-group, C row-group
    const int n0  = blockIdx.x * 16 + w * 4 + q;   // lane's output node

    // ---- stage H~ gate [n][k] + init cols 64..66 ----
    for (int i = tid; i < 4096; i += 256) {
        int k = i >> 6, n = i & 63;
        WTH[n * 72 + k] = (_Float16)PP[8192 + i];
    }
    for (int i = tid; i < 64 * 8; i += 256) {
        int n = i >> 3, kk = i & 7;
        float v = 0.f;
        if (kk == 0)      v = PP[12288 + 2 * 128 + n];
        else if (kk == 1) v = PP[12288 + 2 * 128 + 64 + n];
        else if (kk == 2) v = PP[12672 + 2 * 64 + n];
        WTH[n * 72 + 64 + kk] = (_Float16)v;
    }
    for (int i = tid; i < 32; i += 256) WTH[64 * 72 + i] = (_Float16)0.f;
    // ---- stage Z,R init rows ----
    for (int i = tid; i < 2 * 64 * 8; i += 256) {
        int g = i >> 9, rem = i & 511, n = rem >> 3, kk = rem & 7;
        float v = 0.f;
        if (kk == 0)      v = PP[12288 + g * 128 + n];
        else if (kk == 1) v = PP[12288 + g * 128 + 64 + n];
        else if (kk == 2) v = PP[12672 + g * 64 + n];
        WIZR[(g * 64 + n) * 8 + kk] = (_Float16)v;
    }
    for (int i = tid; i < 32; i += 256) WIZR[1024 + i] = (_Float16)0.f;

    // ---- Z, R gate B-fragments -> registers (loop-invariant) ----
    v8h BZ[4][2], BR[4][2];
    #pragma unroll
    for (int nt = 0; nt < 4; ++nt) {
        #pragma unroll
        for (int c = 0; c < 2; ++c) {
            #pragma unroll
            for (int i = 0; i < 8; ++i) {
                int k = c * 32 + q * 8 + i;
                BZ[nt][c][i] = (_Float16)PP[k * 64 + nt * 16 + m];
                BR[nt][c][i] = (_Float16)PP[4096 + k * 64 + nt * 16 + m];
            }
        }
    }
    // lin B-fragments + bias
    v8h linB0, linB1;
    #pragma unroll
    for (int i = 0; i < 8; ++i) {
        linB0[i] = (_Float16)PP[12864 + (q * 8 + i) * 16 + m];
        linB1[i] = (_Float16)PP[12864 + (32 + q * 8 + i) * 16 + m];
    }
    const float linbv = PP[13888 + m];

    // ---- aggregation prologue: block's 16 nodes into aggL ----
    {
        const int nl = tid >> 4;            // node 0..15
        const int u  = tid & 15;            // 6 j's each
        const int ng = blockIdx.x * 16 + nl;
        const int c  = min(cnt[ng], CAP);
        const float dn = rsqrtf(1.0f + degf[ng]);
        const v2h* x2 = (const v2h*)xAll;
        const int jb = u * 6;               // even -> v2h index u*3
        float acc[6];
        {
            v2h a = x2[(size_t)ng * 48 + u * 3];
            v2h b = x2[(size_t)ng * 48 + u * 3 + 1];
            v2h e = x2[(size_t)ng * 48 + u * 3 + 2];
            float c0 = dn * dn;
            acc[0] = c0 * (float)a.x; acc[1] = c0 * (float)a.y;
            acc[2] = c0 * (float)b.x; acc[3] = c0 * (float)b.y;
            acc[4] = c0 * (float)e.x; acc[5] = c0 * (float)e.y;
        }
        for (int i = 0; i < c; ++i) {
            int2 rec = bucket[ng * CAP + i];
            int s = rec.x;
            float cc = __int_as_float(rec.y) * dn * rsqrtf(1.0f + degf[s]);
            v2h a = x2[(size_t)s * 48 + u * 3];
            v2h b = x2[(size_t)s * 48 + u * 3 + 1];
            v2h e = x2[(size_t)s * 48 + u * 3 + 2];
            acc[0] = fmaf(cc, (float)a.x, acc[0]);
            acc[1] = fmaf(cc, (float)a.y, acc[1]);
            acc[2] = fmaf(cc, (float)b.x, acc[2]);
            acc[3] = fmaf(cc, (float)b.y, acc[3]);
            acc[4] = fmaf(cc, (float)e.x, acc[4]);
            acc[5] = fmaf(cc, (float)e.y, acc[5]);
        }
        #pragma unroll
        for (int jj = 0; jj < 6; ++jj) aggL[nl * 96 + jb + jj] = acc[jj];
    }
    __syncthreads();   // staging + aggregation visible

    _Float16* __restrict__ Hw = &Hm[w][0];
    const int wsw = (q & 2) << 3;                  // write column swizzle
    const _Float16* __restrict__ Ard = Hw + m * 72 + ((q ^ ((m >> 2) & 2)) * 8);
    // aI source: local row w*16+m -> node-local (w*4 + (m>>2)), b = m&3
    const int aggBase = (w * 4 + (m >> 2)) * 96 + (m & 3) * 2;

    float Hold[4][4];                 // fp32 H master, C-layout [ntile][reg]
    #pragma unroll
    for (int nt = 0; nt < 4; ++nt)
        #pragma unroll
        for (int r = 0; r < 4; ++r) Hold[nt][r] = 0.f;
    v8h aH0{}, aH1{};                 // A-fragments of H (zero at t=0)

    const v4f zeroc = {0.f, 0.f, 0.f, 0.f};

    for (int t = 0; t < TSTEPS; ++t) {
        // init A-fragment: [a0, a1, 1, 0...] on q=0 lanes, else 0
        v8h aI{};
        if (q == 0) {
            const float2 av = *(const float2*)&aggL[aggBase + t * 8];
            aI[0] = (_Float16)av.x;
            aI[1] = (_Float16)av.y;
            aI[2] = (_Float16)1.0f;
        }

        // ---- Z, R: init (LDS B) + 2 register-B MFMAs per n-tile ----
        v4f accZ[4], accR[4];
        #pragma unroll
        for (int nt = 0; nt < 4; ++nt) {
            const v8h bIz = *(const v8h*)&WIZR[(0 * 64 + nt * 16 + m) * 8 + q * 8];
            const v8h bIr = *(const v8h*)&WIZR[(1 * 64 + nt * 16 + m) * 8 + q * 8];
            accZ[nt] = __builtin_amdgcn_mfma_f32_16x16x32_f16(aI,  bIz,       zeroc,    0, 0, 0);
            accZ[nt] = __builtin_amdgcn_mfma_f32_16x16x32_f16(aH0, BZ[nt][0], accZ[nt], 0, 0, 0);
            accZ[nt] = __builtin_amdgcn_mfma_f32_16x16x32_f16(aH1, BZ[nt][1], accZ[nt], 0, 0, 0);
            accR[nt] = __builtin_amdgcn_mfma_f32_16x16x32_f16(aI,  bIr,       zeroc,    0, 0, 0);
            accR[nt] = __builtin_amdgcn_mfma_f32_16x16x32_f16(aH0, BR[nt][0], accR[nt], 0, 0, 0);
            accR[nt] = __builtin_amdgcn_mfma_f32_16x16x32_f16(aH1, BR[nt][1], accR[nt], 0, 0, 0);
        }

        // ---- gates; write HR (fp16, swizzled) for H~'s A-operand ----
        float Z[4][4];
        #pragma unroll
        for (int nt = 0; nt < 4; ++nt) {
            #pragma unroll
            for (int r = 0; r < 4; ++r) {
                Z[nt][r] = fsigmoid(accZ[nt][r]);
                float hr = Hold[nt][r] * fsigmoid(accR[nt][r]);
                Hw[(q * 4 + r) * 72 + ((nt * 16 + m) ^ wsw)] = (_Float16)hr;
            }
        }
        __threadfence_block();   // intra-wave LDS visibility
        const v8h aP0 = *(const v8h*)Ard;
        const v8h aP1 = *(const v8h*)(Ard + 32);

        // ---- H_tilde (B from LDS WTH) ----
        v4f accH[4];
        #pragma unroll
        for (int nt = 0; nt < 4; ++nt) {
            const _Float16* bh = &WTH[(nt * 16 + m) * 72 + q * 8];
            accH[nt] = __builtin_amdgcn_mfma_f32_16x16x32_f16(aI,  *(const v8h*)(bh + 64), zeroc,    0, 0, 0);
            accH[nt] = __builtin_amdgcn_mfma_f32_16x16x32_f16(aP0, *(const v8h*)bh,        accH[nt], 0, 0, 0);
            accH[nt] = __builtin_amdgcn_mfma_f32_16x16x32_f16(aP1, *(const v8h*)(bh + 32), accH[nt], 0, 0, 0);
        }

        // ---- combine; update register H; write Hn (swizzled) ----
        #pragma unroll
        for (int nt = 0; nt < 4; ++nt) {
            #pragma unroll
            for (int r = 0; r < 4; ++r) {
                float ht = fmaf(2.0f, fsigmoid(2.0f * accH[nt][r]), -1.0f);   // tanh
                float hn = Z[nt][r] * Hold[nt][r] + (1.f - Z[nt][r]) * ht;
                Hold[nt][r] = hn;
                Hw[(q * 4 + r) * 72 + ((nt * 16 + m) ^ wsw)] = (_Float16)hn;
            }
        }
        __threadfence_block();
        aH0 = *(const v8h*)Ard;          // reused next step's Z/R
        aH1 = *(const v8h*)(Ard + 32);

        // ---- output: relu(Hn) @ lin + lin_b ----
        const v8h zz{};
        v8h r0 = __builtin_elementwise_max(aH0, zz);
        v8h r1 = __builtin_elementwise_max(aH1, zz);
        v4f accO = {linbv, linbv, linbv, linbv};
        accO = __builtin_amdgcn_mfma_f32_16x16x32_f16(r0, linB0, accO, 0, 0, 0);
        accO = __builtin_amdgcn_mfma_f32_16x16x32_f16(r1, linB1, accO, 0, 0, 0);
        #pragma unroll
        for (int r = 0; r < 4; ++r)      // C row q*4+r -> (n0, b=r), col m
            out[(((size_t)r * TSTEPS + t) * NN + n0) * 16 + m] = accO[r];
    }
}

// ---------------- launch ----------------

extern "C" void kernel_launch(void* const* d_in, const int* in_sizes, int n_in,
                              void* d_out, int out_size, void* d_ws, size_t ws_size,
                              hipStream_t stream) {
    const float* x   = (const float*)d_in[0];
    const int*   ei  = (const int*)d_in[1];
    const float* ew  = (const float*)d_in[2];
    const float* Wz  = (const float*)d_in[3];
    const float* bz  = (const float*)d_in[4];
    const float* Wr  = (const float*)d_in[5];
    const float* br  = (const float*)d_in[6];
    const float* Wh  = (const float*)d_in[7];
    const float* bh  = (const float*)d_in[8];
    const float* Lz  = (const float*)d_in[9];
    const float* Lz_b= (const float*)d_in[10];
    const float* Lr  = (const float*)d_in[11];
    const float* Lr_b= (const float*)d_in[12];
    const float* Lh  = (const float*)d_in[13];
    const float* Lh_b= (const float*)d_in[14];
    const float* lw  = (const float*)d_in[15];
    const float* lb  = (const float*)d_in[16];
    float* out = (float*)d_out;

    char* ws = (char*)d_ws;
    size_t off = 0;
    auto alloc = [&](size_t bytes) -> char* {
        char* p = ws + off;
        off += (bytes + 15) & ~(size_t)15;
        return p;
    };
    _Float16* xAll = (_Float16*)alloc((size_t)XTN * 2);
    float* PP      = (float*)alloc(13904 * 4);
    int2*  bucket  = (int2*) alloc((size_t)NN * CAP * 8);
    int*   cnt     = (int*)  alloc(NN * 4);   // cnt and degf adjacent: one memset
    float* degf    = (float*)alloc(NN * 4);

    const int* srcp = ei;
    const int* dstp = ei + NE;

    hipMemsetAsync(cnt, 0, 2 * NN * sizeof(int), stream);   // cnt + degf
    setup_kernel<<<(NE + 255) / 256, 256, 0, stream>>>(x, srcp, dstp, ew, cnt, degf,
                                                       bucket, xAll,
                                                       Wz, bz, Wr, br, Wh, bh,
                                                       Lz, Lz_b, Lr, Lr_b, Lh, Lh_b,
                                                       lw, lb, PP);
    fused_kernel<<<NN / 16, 256, 0, stream>>>(xAll, bucket, cnt, degf, PP, out);
}

// Round 13
// 219.437 us; speedup vs baseline: 1.1509x; 1.1509x over previous
//
#include <hip/hip_runtime.h>
#include <cstdint>
#include <cstddef>

#define NN      10000
#define NE      320000
#define FINF    2
#define HIDN    64
#define OUTN    16
#define BBATCH  4
#define TSTEPS  12
#define NBROWS  (NN * BBATCH)                    // 40000 (n-major, row = n*B + b)
#define XTN     (TSTEPS * NN * BBATCH * FINF)    // 960000
#define CAP     96                               // bucket capacity; P(deg>96) ~ 1e-18

typedef _Float16 v8h __attribute__((ext_vector_type(8)));
typedef _Float16 v2h __attribute__((ext_vector_type(2)));
typedef float    v4f __attribute__((ext_vector_type(4)));

// ---------------- fused setup: transpose + bucket-scatter + param fold ------
// Grid 1250x256 = 320000 threads = 1/edge. Transpose: thread per (b,n), 96B
// coalesced read, 12 x 4B half2 writes. xAll[n][96] fp16, j = t*8 + b*2 + f.
// PP layout (floats):
//   [0)      Lzb[64][64]   (k-major [k][j])
//   [4096)   Lrb[64][64]
//   [8192)   Lhb[64][64]
//   [12288)  W2[3][2][64]  = Wg @ Lg_top
//   [12672)  b2[3][64]     = bg @ Lg_top + Lg_b
//   [12864)  lin_w[64][16]
//   [13888)  lin_b[16]     (total 13904)
extern "C" __global__ void setup_kernel(const float* __restrict__ x,
                             const int* __restrict__ src, const int* __restrict__ dst,
                             const float* __restrict__ ew,
                             int* __restrict__ cnt, float* __restrict__ degf,
                             int2* __restrict__ bucket, _Float16* __restrict__ xAll,
                             const float* __restrict__ Wz, const float* __restrict__ bz,
                             const float* __restrict__ Wr, const float* __restrict__ br,
                             const float* __restrict__ Wh, const float* __restrict__ bh,
                             const float* __restrict__ Lz, const float* __restrict__ Lz_b,
                             const float* __restrict__ Lr, const float* __restrict__ Lr_b,
                             const float* __restrict__ Lh, const float* __restrict__ Lh_b,
                             const float* __restrict__ linw, const float* __restrict__ linb,
                             float* __restrict__ PP) {
    int idx = blockIdx.x * 256 + threadIdx.x;
    // transpose: thread per (b,n): read 24 consecutive floats, write 12 half2
    if (idx < BBATCH * NN) {
        int b = idx / NN;
        int n = idx - b * NN;
        const float* xp = x + (size_t)idx * (FINF * TSTEPS);   // (b*NN+n)*24
        v2h* xo = (v2h*)xAll;                                  // pair (f=0,f=1)
        #pragma unroll
        for (int t = 0; t < TSTEPS; ++t) {
            v2h p;
            p.x = (_Float16)xp[t];
            p.y = (_Float16)xp[TSTEPS + t];
            xo[n * 48 + t * 4 + b] = p;
        }
    }
    // bucket scatter by dst + weighted degree (1 edge per thread)
    if (idx < NE) {
        int d = dst[idx];
        int s = src[idx];
        float w = ew[idx];
        int p = atomicAdd(&cnt[d], 1);
        if (p < CAP) {
            int2 rec;
            rec.x = s;
            rec.y = __float_as_int(w);
            bucket[d * CAP + p] = rec;
        }
        atomicAdd(&degf[d], w);
    }
    // parameter folding
    if (idx < 13904) {
        const float* Lg[3]    = {Lz, Lr, Lh};
        const float* Lbias[3] = {Lz_b, Lr_b, Lh_b};
        const float* Wg[3]    = {Wz, Wr, Wh};
        const float* bg[3]    = {bz, br, bh};
        int i = idx;
        if (i < 12288) {
            int g = i >> 12, rr = (i >> 6) & 63, j = i & 63;
            PP[i] = Lg[g][(64 + rr) * 64 + j];
        } else if (i < 12672) {
            int i2 = i - 12288;
            int g = i2 >> 7, f = (i2 >> 6) & 1, j = i2 & 63;
            float s = 0.f;
            for (int k = 0; k < 64; ++k) s = fmaf(Wg[g][f * 64 + k], Lg[g][k * 64 + j], s);
            PP[i] = s;
        } else if (i < 12864) {
            int i3 = i - 12672;
            int g = i3 >> 6, j = i3 & 63;
            float s = Lbias[g][j];
            for (int k = 0; k < 64; ++k) s = fmaf(bg[g][k], Lg[g][k * 64 + j], s);
            PP[i] = s;
        } else if (i < 13888) {
            PP[i] = linw[i - 12864];
        } else {
            PP[i] = linb[i - 13888];
        }
    }
}

// ---------------- fused aggregate + recurrent GRU ----------------
// 625 blocks x 256 thr (4 waves, wave owns M=16 rows). Block bk's rows are
// nodes 16bk..16bk+15. Aggregation prologue is TWO-PHASE (the R12 one-phase
// version serialized a bucket->degf dependent chain per node, +40us):
//   A: 16 lanes/node stage edges i=u,u+16,.. -> 16 independent L2 chains/node,
//      coefficients into LDS (s_src/s_c).
//   B: 6-FMA-per-edge pass; s,cc from LDS (same-addr broadcast = free), xAll
//      gather 12B/lane contiguous, iterations independent -> pipelined.
// Then one __syncthreads and the R11 t-loop reading aggL.
__device__ __forceinline__ float fsigmoid(float x) {
    return 1.0f / (1.0f + __expf(-x));
}

extern "C" __global__ __launch_bounds__(256, 3)
void fused_kernel(const _Float16* __restrict__ xAll, const int2* __restrict__ bucket,
                  const int* __restrict__ cnt, const float* __restrict__ degf,
                  const float* __restrict__ PP, float* __restrict__ out) {
    __shared__ _Float16 WTH[64 * 72 + 32];      // H~: [n][k<64 | 64..66 init], pad
    __shared__ _Float16 WIZR[2 * 64 * 8 + 32];  // Z,R init: [g][n][0..7], pad
    __shared__ _Float16 Hm[4][16 * 72];         // per-wave H [row][col^swz]
    __shared__ float    aggL[16 * 96];          // block's 16 nodes x 96 (fp32)
    __shared__ int      s_src[16 * CAP];        // staged edge sources
    __shared__ float    s_c[16 * CAP];          // staged edge coefficients
    __shared__ int      s_cnt[16];
    const int tid = threadIdx.x;
    const int w   = tid >> 6;
    const int l   = tid & 63;
    const int m   = l & 15;          // A row / B,C col within 16x16 tile
    const int q   = l >> 4;          // quad: A k-group, C row-group
    const int n0  = blockIdx.x * 16 + w * 4 + q;   // lane's output node

    // ---- phase A: parallel edge staging (16 chains per node) ----
    {
        const int nl = tid >> 4;            // node 0..15
        const int u  = tid & 15;
        const int ng = blockIdx.x * 16 + nl;
        const int c  = min(cnt[ng], CAP);
        if (u == 0) s_cnt[nl] = c;
        const float dn = rsqrtf(1.0f + degf[ng]);
        for (int i = u; i < c; i += 16) {
            int2 rec = bucket[ng * CAP + i];
            int s = rec.x;
            s_src[nl * CAP + i] = s;
            s_c[nl * CAP + i]   = __int_as_float(rec.y) * dn * rsqrtf(1.0f + degf[s]);
        }
    }

    // ---- stage H~ gate [n][k] + init cols 64..66 (overlaps phase A latency) ----
    for (int i = tid; i < 4096; i += 256) {
        int k = i >> 6, n = i & 63;
        WTH[n * 72 + k] = (_Float16)PP[8192 + i];
    }
    for (int i = tid; i < 64 * 8; i += 256) {
        int n = i >> 3, kk = i & 7;
        float v = 0.f;
        if (kk == 0)      v = PP[12288 + 2 * 128 + n];
        else if (kk == 1) v = PP[12288 + 2 * 128 + 64 + n];
        else if (kk == 2) v = PP[12672 + 2 * 64 + n];
        WTH[n * 72 + 64 + kk] = (_Float16)v;
    }
    for (int i = tid; i < 32; i += 256) WTH[64 * 72 + i] = (_Float16)0.f;
    // ---- stage Z,R init rows ----
    for (int i = tid; i < 2 * 64 * 8; i += 256) {
        int g = i >> 9, rem = i & 511, n = rem >> 3, kk = rem & 7;
        float v = 0.f;
        if (kk == 0)      v = PP[12288 + g * 128 + n];
        else if (kk == 1) v = PP[12288 + g * 128 + 64 + n];
        else if (kk == 2) v = PP[12672 + g * 64 + n];
        WIZR[(g * 64 + n) * 8 + kk] = (_Float16)v;
    }
    for (int i = tid; i < 32; i += 256) WIZR[1024 + i] = (_Float16)0.f;

    __syncthreads();   // phase A + weight staging visible

    // ---- phase B: throughput aggregation into aggL ----
    {
        const int nl = tid >> 4;
        const int u  = tid & 15;
        const int ng = blockIdx.x * 16 + nl;
        const int c  = s_cnt[nl];
        const float dn = rsqrtf(1.0f + degf[ng]);   // L1-hot
        const v2h* x2 = (const v2h*)xAll;
        float acc[6];
        {
            v2h a = x2[(size_t)ng * 48 + u * 3];
            v2h b = x2[(size_t)ng * 48 + u * 3 + 1];
            v2h e = x2[(size_t)ng * 48 + u * 3 + 2];
            float c0 = dn * dn;
            acc[0] = c0 * (float)a.x; acc[1] = c0 * (float)a.y;
            acc[2] = c0 * (float)b.x; acc[3] = c0 * (float)b.y;
            acc[4] = c0 * (float)e.x; acc[5] = c0 * (float)e.y;
        }
        for (int i = 0; i < c; ++i) {
            int s    = s_src[nl * CAP + i];       // same-addr broadcast
            float cc = s_c[nl * CAP + i];
            v2h a = x2[(size_t)s * 48 + u * 3];
            v2h b = x2[(size_t)s * 48 + u * 3 + 1];
            v2h e = x2[(size_t)s * 48 + u * 3 + 2];
            acc[0] = fmaf(cc, (float)a.x, acc[0]);
            acc[1] = fmaf(cc, (float)a.y, acc[1]);
            acc[2] = fmaf(cc, (float)b.x, acc[2]);
            acc[3] = fmaf(cc, (float)b.y, acc[3]);
            acc[4] = fmaf(cc, (float)e.x, acc[4]);
            acc[5] = fmaf(cc, (float)e.y, acc[5]);
        }
        #pragma unroll
        for (int jj = 0; jj < 6; ++jj) aggL[nl * 96 + u * 6 + jj] = acc[jj];
    }

    // ---- Z, R gate B-fragments -> registers (loop-invariant) ----
    v8h BZ[4][2], BR[4][2];
    #pragma unroll
    for (int nt = 0; nt < 4; ++nt) {
        #pragma unroll
        for (int c = 0; c < 2; ++c) {
            #pragma unroll
            for (int i = 0; i < 8; ++i) {
                int k = c * 32 + q * 8 + i;
                BZ[nt][c][i] = (_Float16)PP[k * 64 + nt * 16 + m];
                BR[nt][c][i] = (_Float16)PP[4096 + k * 64 + nt * 16 + m];
            }
        }
    }
    // lin B-fragments + bias
    v8h linB0, linB1;
    #pragma unroll
    for (int i = 0; i < 8; ++i) {
        linB0[i] = (_Float16)PP[12864 + (q * 8 + i) * 16 + m];
        linB1[i] = (_Float16)PP[12864 + (32 + q * 8 + i) * 16 + m];
    }
    const float linbv = PP[13888 + m];

    __syncthreads();   // aggL visible

    _Float16* __restrict__ Hw = &Hm[w][0];
    const int wsw = (q & 2) << 3;                  // write column swizzle
    const _Float16* __restrict__ Ard = Hw + m * 72 + ((q ^ ((m >> 2) & 2)) * 8);
    // aI source: local row w*16+m -> node-local (w*4 + (m>>2)), b = m&3
    const int aggBase = (w * 4 + (m >> 2)) * 96 + (m & 3) * 2;

    float Hold[4][4];                 // fp32 H master, C-layout [ntile][reg]
    #pragma unroll
    for (int nt = 0; nt < 4; ++nt)
        #pragma unroll
        for (int r = 0; r < 4; ++r) Hold[nt][r] = 0.f;
    v8h aH0{}, aH1{};                 // A-fragments of H (zero at t=0)

    const v4f zeroc = {0.f, 0.f, 0.f, 0.f};

    for (int t = 0; t < TSTEPS; ++t) {
        // init A-fragment: [a0, a1, 1, 0...] on q=0 lanes, else 0
        v8h aI{};
        if (q == 0) {
            const float2 av = *(const float2*)&aggL[aggBase + t * 8];
            aI[0] = (_Float16)av.x;
            aI[1] = (_Float16)av.y;
            aI[2] = (_Float16)1.0f;
        }

        // ---- Z, R: init (LDS B) + 2 register-B MFMAs per n-tile ----
        v4f accZ[4], accR[4];
        #pragma unroll
        for (int nt = 0; nt < 4; ++nt) {
            const v8h bIz = *(const v8h*)&WIZR[(0 * 64 + nt * 16 + m) * 8 + q * 8];
            const v8h bIr = *(const v8h*)&WIZR[(1 * 64 + nt * 16 + m) * 8 + q * 8];
            accZ[nt] = __builtin_amdgcn_mfma_f32_16x16x32_f16(aI,  bIz,       zeroc,    0, 0, 0);
            accZ[nt] = __builtin_amdgcn_mfma_f32_16x16x32_f16(aH0, BZ[nt][0], accZ[nt], 0, 0, 0);
            accZ[nt] = __builtin_amdgcn_mfma_f32_16x16x32_f16(aH1, BZ[nt][1], accZ[nt], 0, 0, 0);
            accR[nt] = __builtin_amdgcn_mfma_f32_16x16x32_f16(aI,  bIr,       zeroc,    0, 0, 0);
            accR[nt] = __builtin_amdgcn_mfma_f32_16x16x32_f16(aH0, BR[nt][0], accR[nt], 0, 0, 0);
            accR[nt] = __builtin_amdgcn_mfma_f32_16x16x32_f16(aH1, BR[nt][1], accR[nt], 0, 0, 0);
        }

        // ---- gates; write HR (fp16, swizzled) for H~'s A-operand ----
        float Z[4][4];
        #pragma unroll
        for (int nt = 0; nt < 4; ++nt) {
            #pragma unroll
            for (int r = 0; r < 4; ++r) {
                Z[nt][r] = fsigmoid(accZ[nt][r]);
                float hr = Hold[nt][r] * fsigmoid(accR[nt][r]);
                Hw[(q * 4 + r) * 72 + ((nt * 16 + m) ^ wsw)] = (_Float16)hr;
            }
        }
        __threadfence_block();   // intra-wave LDS visibility
        const v8h aP0 = *(const v8h*)Ard;
        const v8h aP1 = *(const v8h*)(Ard + 32);

        // ---- H_tilde (B from LDS WTH) ----
        v4f accH[4];
        #pragma unroll
        for (int nt = 0; nt < 4; ++nt) {
            const _Float16* bh = &WTH[(nt * 16 + m) * 72 + q * 8];
            accH[nt] = __builtin_amdgcn_mfma_f32_16x16x32_f16(aI,  *(const v8h*)(bh + 64), zeroc,    0, 0, 0);
            accH[nt] = __builtin_amdgcn_mfma_f32_16x16x32_f16(aP0, *(const v8h*)bh,        accH[nt], 0, 0, 0);
            accH[nt] = __builtin_amdgcn_mfma_f32_16x16x32_f16(aP1, *(const v8h*)(bh + 32), accH[nt], 0, 0, 0);
        }

        // ---- combine; update register H; write Hn (swizzled) ----
        #pragma unroll
        for (int nt = 0; nt < 4; ++nt) {
            #pragma unroll
            for (int r = 0; r < 4; ++r) {
                float ht = fmaf(2.0f, fsigmoid(2.0f * accH[nt][r]), -1.0f);   // tanh
                float hn = Z[nt][r] * Hold[nt][r] + (1.f - Z[nt][r]) * ht;
                Hold[nt][r] = hn;
                Hw[(q * 4 + r) * 72 + ((nt * 16 + m) ^ wsw)] = (_Float16)hn;
            }
        }
        __threadfence_block();
        aH0 = *(const v8h*)Ard;          // reused next step's Z/R
        aH1 = *(const v8h*)(Ard + 32);

        // ---- output: relu(Hn) @ lin + lin_b ----
        const v8h zz{};
        v8h r0 = __builtin_elementwise_max(aH0, zz);
        v8h r1 = __builtin_elementwise_max(aH1, zz);
        v4f accO = {linbv, linbv, linbv, linbv};
        accO = __builtin_amdgcn_mfma_f32_16x16x32_f16(r0, linB0, accO, 0, 0, 0);
        accO = __builtin_amdgcn_mfma_f32_16x16x32_f16(r1, linB1, accO, 0, 0, 0);
        #pragma unroll
        for (int r = 0; r < 4; ++r)      // C row q*4+r -> (n0, b=r), col m
            out[(((size_t)r * TSTEPS + t) * NN + n0) * 16 + m] = accO[r];
    }
}

// ---------------- launch ----------------

extern "C" void kernel_launch(void* const* d_in, const int* in_sizes, int n_in,
                              void* d_out, int out_size, void* d_ws, size_t ws_size,
                              hipStream_t stream) {
    const float* x   = (const float*)d_in[0];
    const int*   ei  = (const int*)d_in[1];
    const float* ew  = (const float*)d_in[2];
    const float* Wz  = (const float*)d_in[3];
    const float* bz  = (const float*)d_in[4];
    const float* Wr  = (const float*)d_in[5];
    const float* br  = (const float*)d_in[6];
    const float* Wh  = (const float*)d_in[7];
    const float* bh  = (const float*)d_in[8];
    const float* Lz  = (const float*)d_in[9];
    const float* Lz_b= (const float*)d_in[10];
    const float* Lr  = (const float*)d_in[11];
    const float* Lr_b= (const float*)d_in[12];
    const float* Lh  = (const float*)d_in[13];
    const float* Lh_b= (const float*)d_in[14];
    const float* lw  = (const float*)d_in[15];
    const float* lb  = (const float*)d_in[16];
    float* out = (float*)d_out;

    char* ws = (char*)d_ws;
    size_t off = 0;
    auto alloc = [&](size_t bytes) -> char* {
        char* p = ws + off;
        off += (bytes + 15) & ~(size_t)15;
        return p;
    };
    _Float16* xAll = (_Float16*)alloc((size_t)XTN * 2);
    float* PP      = (float*)alloc(13904 * 4);
    int2*  bucket  = (int2*) alloc((size_t)NN * CAP * 8);
    int*   cnt     = (int*)  alloc(NN * 4);   // cnt and degf adjacent: one memset
    float* degf    = (float*)alloc(NN * 4);

    const int* srcp = ei;
    const int* dstp = ei + NE;

    hipMemsetAsync(cnt, 0, 2 * NN * sizeof(int), stream);   // cnt + degf
    setup_kernel<<<(NE + 255) / 256, 256, 0, stream>>>(x, srcp, dstp, ew, cnt, degf,
                                                       bucket, xAll,
                                                       Wz, bz, Wr, br, Wh, bh,
                                                       Lz, Lz_b, Lr, Lr_b, Lh, Lh_b,
                                                       lw, lb, PP);
    fused_kernel<<<NN / 16, 256, 0, stream>>>(xAll, bucket, cnt, degf, PP, out);
}